// Round 1
// baseline (227.794 us; speedup 1.0000x reference)
//
#include <hip/hip_runtime.h>
#include <stdint.h>

#define S_ 512
#define B_ 32
#define D_ 256

typedef __attribute__((ext_vector_type(8))) short bf16x8;
typedef __attribute__((ext_vector_type(4))) float f32x4;

__device__ __forceinline__ unsigned short f2bf(float f) {
    union { float f; uint32_t u; } v; v.f = f;
    uint32_t r = v.u + 0x7FFFu + ((v.u >> 16) & 1u);
    return (unsigned short)(r >> 16);
}
__device__ __forceinline__ float bf2f(unsigned short h) {
    union { uint32_t u; float f; } v; v.u = ((uint32_t)h) << 16;
    return v.f;
}

// ---------------- prep: f32 -> bf16 copies of x, W, W_out ----------------
__global__ __launch_bounds__(256) void prep_kernel(
    const float* __restrict__ gcn, const float* __restrict__ W,
    const float* __restrict__ Wout,
    unsigned short* __restrict__ Xbf, unsigned short* __restrict__ Wbf,
    unsigned short* __restrict__ WoutBf)
{
    int i = blockIdx.x * 256 + threadIdx.x;
    int stride = gridDim.x * 256;
    for (int t = i; t < B_ * S_ * D_; t += stride) Xbf[t] = f2bf(gcn[t]);
    for (int t = i; t < 6 * D_ * D_; t += stride) Wbf[t] = f2bf(W[t]);
    for (int t = i; t < D_ * 6 * D_; t += stride) WoutBf[t] = f2bf(Wout[t]);
}

// ---------------- fused layer: Ax = adj@cur ; y = relu(((Ax+cur)@W^T + 2b)/denom) ----------------
// grid (8, 32): blockIdx.x = s-block (64 rows), blockIdx.y = batch. 256 threads = 4 waves.
// Wave w owns output cols [64w, 64w+64). MFMA 16x16x32 bf16.
__global__ __launch_bounds__(256) void layer_kernel(
    const float* __restrict__ adjH,          // adj + h*B*S*S   [B,S,S] f32
    const unsigned short* __restrict__ cur,  // [B,S,D] bf16
    const unsigned short* __restrict__ Wl,   // Wbf + idx*D*D   [e][d] bf16
    const float* __restrict__ bl,            // b + idx*D       [e] f32
    unsigned short* __restrict__ yOut)       // [B,S,D] bf16
{
    __shared__ __align__(16) unsigned short As[64 * 40];   // adj tile [64 s][32 t], stride 40
    __shared__ __align__(16) unsigned short Bs[32 * 258];  // cur tile [32 t][256 d], stride 258
    __shared__ __align__(16) unsigned short Ps[64 * 264];  // P = Ax+cur [64 s][256 d], stride 264
    __shared__ float Dsh[64];                              // 1/(rowsum+1)

    const int tid  = threadIdx.x;
    const int lane = tid & 63;
    const int w    = tid >> 6;
    const int lm   = lane & 15;
    const int g    = lane >> 4;
    const int s0   = blockIdx.x * 64;
    const int b    = blockIdx.y;

    const float* adjB = adjH + (int64_t)b * S_ * S_;
    const unsigned short* curB = cur + (int64_t)b * S_ * D_;

    f32x4 acc[4][4];
#pragma unroll
    for (int i = 0; i < 4; i++)
#pragma unroll
        for (int j = 0; j < 4; j++) acc[i][j] = {0.f, 0.f, 0.f, 0.f};

    // staging maps
    const int ar = tid >> 2;          // 0..63 : A row
    const int ac = (tid & 3) * 8;     // 0,8,16,24 : A col chunk
    const int bt = tid >> 3;          // 0..31 : B row (t)
    const int bd = (tid & 7) * 32;    // B col chunk

    float rowsum = 0.f;

    for (int t0 = 0; t0 < S_; t0 += 32) {
        // stage A: adj[s0+ar][t0+ac .. +8] f32 -> bf16, also accumulate row sum (denom)
        {
            const float* src = adjB + (int64_t)(s0 + ar) * S_ + t0 + ac;
            float4 v0 = *(const float4*)(src);
            float4 v1 = *(const float4*)(src + 4);
            rowsum += v0.x + v0.y + v0.z + v0.w + v1.x + v1.y + v1.z + v1.w;
            uint4 p;
            p.x = (uint32_t)f2bf(v0.x) | ((uint32_t)f2bf(v0.y) << 16);
            p.y = (uint32_t)f2bf(v0.z) | ((uint32_t)f2bf(v0.w) << 16);
            p.z = (uint32_t)f2bf(v1.x) | ((uint32_t)f2bf(v1.y) << 16);
            p.w = (uint32_t)f2bf(v1.z) | ((uint32_t)f2bf(v1.w) << 16);
            *(uint4*)&As[ar * 40 + ac] = p;
        }
        // stage B: cur[t0+bt][bd .. bd+32] (already bf16): 64B per thread
        {
            const unsigned short* src = curB + (int64_t)(t0 + bt) * D_ + bd;
            uint4 q0 = *(const uint4*)(src);
            uint4 q1 = *(const uint4*)(src + 8);
            uint4 q2 = *(const uint4*)(src + 16);
            uint4 q3 = *(const uint4*)(src + 24);
            uint32_t* dst = (uint32_t*)&Bs[bt * 258 + bd];
            dst[0] = q0.x; dst[1] = q0.y; dst[2]  = q0.z; dst[3]  = q0.w;
            dst[4] = q1.x; dst[5] = q1.y; dst[6]  = q1.z; dst[7]  = q1.w;
            dst[8] = q2.x; dst[9] = q2.y; dst[10] = q2.z; dst[11] = q2.w;
            dst[12] = q3.x; dst[13] = q3.y; dst[14] = q3.z; dst[15] = q3.w;
        }
        __syncthreads();

        bf16x8 aF[4];
#pragma unroll
        for (int mi = 0; mi < 4; mi++)
            aF[mi] = *(const bf16x8*)&As[(16 * mi + lm) * 40 + g * 8];
#pragma unroll
        for (int ni = 0; ni < 4; ni++) {
            const int d = 64 * w + 16 * ni + lm;
            bf16x8 bF;
#pragma unroll
            for (int kk = 0; kk < 8; kk++)
                bF[kk] = (short)Bs[(g * 8 + kk) * 258 + d];
#pragma unroll
            for (int mi = 0; mi < 4; mi++)
                acc[mi][ni] = __builtin_amdgcn_mfma_f32_16x16x32_bf16(aF[mi], bF, acc[mi][ni], 0, 0, 0);
        }
        __syncthreads();
    }

    // denom: rowsum held by 4 threads per row (tid = 4*ar + 0..3)
    {
        float rs = rowsum;
        rs += __shfl_xor(rs, 1);
        rs += __shfl_xor(rs, 2);
        if ((tid & 3) == 0) Dsh[ar] = 1.0f / (rs + 1.0f);
    }

    // P = Ax + cur -> Ps (bf16)
#pragma unroll
    for (int mi = 0; mi < 4; mi++)
#pragma unroll
        for (int ni = 0; ni < 4; ni++) {
            const int dcol = 64 * w + 16 * ni + lm;
#pragma unroll
            for (int r = 0; r < 4; r++) {
                const int srow = 16 * mi + 4 * g + r;
                float pv = acc[mi][ni][r] + bf2f(curB[(int64_t)(s0 + srow) * D_ + dcol]);
                Ps[srow * 264 + dcol] = f2bf(pv);
            }
        }
    __syncthreads();

    // mm2: Q[s][e] = sum_d P[s][d] * W[e][d]
#pragma unroll
    for (int i = 0; i < 4; i++)
#pragma unroll
        for (int j = 0; j < 4; j++) acc[i][j] = {0.f, 0.f, 0.f, 0.f};

    for (int kc = 0; kc < 8; kc++) {
        bf16x8 aF[4];
#pragma unroll
        for (int mi = 0; mi < 4; mi++)
            aF[mi] = *(const bf16x8*)&Ps[(16 * mi + lm) * 264 + kc * 32 + g * 8];
#pragma unroll
        for (int ni = 0; ni < 4; ni++) {
            const int e = 64 * w + 16 * ni + lm;
            bf16x8 bF = *(const bf16x8*)&Wl[(int64_t)e * D_ + kc * 32 + g * 8];
#pragma unroll
            for (int mi = 0; mi < 4; mi++)
                acc[mi][ni] = __builtin_amdgcn_mfma_f32_16x16x32_bf16(aF[mi], bF, acc[mi][ni], 0, 0, 0);
        }
    }

    // epilogue: y = relu((Q + 2b) / denom), store bf16
#pragma unroll
    for (int ni = 0; ni < 4; ni++) {
        const int e = 64 * w + 16 * ni + lm;
        const float bv = 2.0f * bl[e];
#pragma unroll
        for (int mi = 0; mi < 4; mi++)
#pragma unroll
            for (int r = 0; r < 4; r++) {
                const int srow = 16 * mi + 4 * g + r;
                float yv = (acc[mi][ni][r] + bv) * Dsh[srow];
                yv = yv > 0.f ? yv : 0.f;
                yOut[(int64_t)b * S_ * D_ + (int64_t)(s0 + srow) * D_ + e] = f2bf(yv);
            }
    }
}

// ---------------- final: out = gcn + b_out + concat(y)@Wout^T ----------------
__global__ __launch_bounds__(256) void final_kernel(
    const unsigned short* __restrict__ yAll,   // [6][B*S*D] bf16
    const unsigned short* __restrict__ WoutBf, // [256][1536] bf16
    const float* __restrict__ gcn,
    const float* __restrict__ bout,
    float* __restrict__ out)
{
    const int tid  = threadIdx.x;
    const int lane = tid & 63;
    const int w    = tid >> 6;
    const int lm   = lane & 15;
    const int g    = lane >> 4;
    const int s0   = blockIdx.x * 64;
    const int b    = blockIdx.y;

    f32x4 acc[4][4];
#pragma unroll
    for (int i = 0; i < 4; i++)
#pragma unroll
        for (int j = 0; j < 4; j++) acc[i][j] = {0.f, 0.f, 0.f, 0.f};

    for (int kc = 0; kc < 48; kc++) {
        const int f0 = kc * 32;
        const int hl = f0 >> 8;      // which (head,layer) slice
        const int e0 = f0 & 255;     // col within that slice
        const unsigned short* yb = yAll + (int64_t)hl * (B_ * S_ * D_) + (int64_t)b * S_ * D_;
        bf16x8 aF[4];
#pragma unroll
        for (int mi = 0; mi < 4; mi++)
            aF[mi] = *(const bf16x8*)&yb[(int64_t)(s0 + 16 * mi + lm) * D_ + e0 + g * 8];
#pragma unroll
        for (int ni = 0; ni < 4; ni++) {
            const int e = 64 * w + 16 * ni + lm;
            bf16x8 bF = *(const bf16x8*)&WoutBf[(int64_t)e * 1536 + f0 + g * 8];
#pragma unroll
            for (int mi = 0; mi < 4; mi++)
                acc[mi][ni] = __builtin_amdgcn_mfma_f32_16x16x32_bf16(aF[mi], bF, acc[mi][ni], 0, 0, 0);
        }
    }

#pragma unroll
    for (int ni = 0; ni < 4; ni++) {
        const int e = 64 * w + 16 * ni + lm;
        const float bo = bout[e];
#pragma unroll
        for (int mi = 0; mi < 4; mi++)
#pragma unroll
            for (int r = 0; r < 4; r++) {
                const int srow = 16 * mi + 4 * g + r;
                const int64_t idx = (int64_t)(b * S_ + s0 + srow) * D_ + e;
                out[idx] = acc[mi][ni][r] + gcn[idx] + bo;
            }
    }
}

extern "C" void kernel_launch(void* const* d_in, const int* in_sizes, int n_in,
                              void* d_out, int out_size, void* d_ws, size_t ws_size,
                              hipStream_t stream) {
    const float* adj  = (const float*)d_in[0];   // [3,32,512,512]
    const float* gcn  = (const float*)d_in[1];   // [32,512,256]
    const float* W    = (const float*)d_in[4];   // [6,256,256]
    const float* bvec = (const float*)d_in[5];   // [6,256]
    const float* Wout = (const float*)d_in[6];   // [256,1536]
    const float* bout = (const float*)d_in[7];   // [256]
    float* out = (float*)d_out;

    unsigned short* Xbf    = (unsigned short*)d_ws;           // 4,194,304 elems
    unsigned short* yAll   = Xbf + (int64_t)B_ * S_ * D_;     // 6 * 4,194,304
    unsigned short* Wbf    = yAll + (int64_t)6 * B_ * S_ * D_;
    unsigned short* WoutBf = Wbf + 6 * D_ * D_;
    // total ws use: (7*4,194,304 + 2*393,216) * 2 bytes ≈ 60.3 MB

    prep_kernel<<<2048, 256, 0, stream>>>(gcn, W, Wout, Xbf, Wbf, WoutBf);

    for (int h = 0; h < 3; h++) {
        for (int l = 0; l < 2; l++) {
            const int idx = h * 2 + l;
            const unsigned short* cur =
                (l == 0) ? Xbf : (yAll + (int64_t)(h * 2) * B_ * S_ * D_);
            layer_kernel<<<dim3(8, 32), 256, 0, stream>>>(
                adj + (int64_t)h * B_ * S_ * S_,
                cur,
                Wbf + (int64_t)idx * D_ * D_,
                bvec + idx * D_,
                yAll + (int64_t)idx * B_ * S_ * D_);
        }
    }

    final_kernel<<<dim3(8, 32), 256, 0, stream>>>(yAll, WoutBf, gcn, bout, out);
}